// Round 6
// baseline (167.206 us; speedup 1.0000x reference)
//
#include <hip/hip_runtime.h>

#define CIN 512
#define COUT 512
#define HH 64
#define WW 64
#define BB 8
#define KTOT 4608   // 512*9

#define XPD 66               // padded spatial dim: index = coord+1, coord in -1..64
#define BUFSH (4 * 66 * 32)  // 8448 shorts per LDS buffer (4 rows x 66 slices x 32 ch)
#define ROWB (66 * 64)       // 4224 bytes per LDS input row

typedef __attribute__((ext_vector_type(8))) short short8;
typedef __attribute__((ext_vector_type(4))) float f32x4;

__device__ inline unsigned short f2bf(float f) {
    unsigned int u = __float_as_uint(f);
    u += 0x7FFFu + ((u >> 16) & 1u);   // round-to-nearest-even
    return (unsigned short)(u >> 16);
}

__device__ inline void gll16(const void* g, void* l) {
    __builtin_amdgcn_global_load_lds(
        (const __attribute__((address_space(1))) unsigned int*)g,
        (__attribute__((address_space(3))) unsigned int*)l, 16, 0, 0);
}

// ---------------- Phase -1: zero the halo ring of XTP ----------------
__global__ __launch_bounds__(256) void zring_kernel(unsigned short* __restrict__ xtp) {
    const int e = blockIdx.x * 256 + threadIdx.x;   // 520*256 >= 8*260*64
    if (e >= BB * 260 * 64) return;
    const int unit = e & 63;
    const int sa = e >> 6;           // 0..2079
    const int b = sa / 260;
    const int s = sa - b * 260;
    int yy, xx;
    if (s < 66)       { yy = 0;        xx = s; }
    else if (s < 132) { yy = 65;       xx = s - 66; }
    else if (s < 196) { yy = s - 131;  xx = 0; }     // rows 1..64
    else              { yy = s - 195;  xx = 65; }    // rows 1..64
    *(short8*)(xtp + ((size_t)(b * XPD + yy) * XPD + xx) * 512 + unit * 8) =
        (short8){0, 0, 0, 0, 0, 0, 0, 0};
}

// ------- Phase 0: x [b][i][y][x] fp32 * (1+style[b][i]) -> XTP [b][y+1][x+1][i] bf16 -------
__global__ __launch_bounds__(256) void xpose_kernel(const float* __restrict__ x,
                                                    const float* __restrict__ style,
                                                    unsigned short* __restrict__ xtp) {
    __shared__ float tile[32 * 65];
    __shared__ float sst[32];
    const int ic = blockIdx.x;   // 16 groups of 32 channels
    const int y  = blockIdx.y;
    const int b  = blockIdx.z;
    const int t  = threadIdx.x;
    if (t < 32) sst[t] = style[b * CIN + ic * 32 + t] + 1.0f;
#pragma unroll
    for (int it = 0; it < 8; ++it) {
        int e = it * 256 + t;
        int ii = e >> 6, xx = e & 63;
        tile[ii * 65 + xx] = x[(((size_t)(b * CIN + ic * 32 + ii) * HH + y) << 6) + xx];
    }
    __syncthreads();
#pragma unroll
    for (int it = 0; it < 8; ++it) {
        int g = it * 256 + t;
        int xx = g >> 5, ii = g & 31;
        xtp[((size_t)(b * XPD + y + 1) * XPD + xx + 1) * 512 + ic * 32 + ii] =
            f2bf(tile[ii * 65 + xx] * sst[ii]);
    }
}

// ---------------- Phase 1a: pack w*c into MFMA fragment layout (batch-independent) -------
// Wpk flat: (((c*9 + tap)*32 + g)*64 + lane)*8 + e ; lane = l4*16+l15 holds
//   W[o = g*16+l15][i = c*32 + l4*8 + e],  c = 16 chunks of 32 input ch.
__global__ __launch_bounds__(256) void wpack_kernel(const float* __restrict__ weight,
                                                    unsigned short* __restrict__ wpk) {
    __shared__ float q[KTOT];
    const int o = blockIdx.x;
    const int t = threadIdx.x;
    const float* wrow = weight + (size_t)o * KTOT;   // e = i*9+tap
    const float cst = 1.0f / sqrtf((float)KTOT);
#pragma unroll
    for (int it = 0; it < 18; ++it) {
        int e = it * 256 + t;
        q[e] = wrow[e] * cst;
    }
    __syncthreads();
    const int g = o >> 4, l15 = o & 15;
    for (int m = t; m < 576; m += 256) {   // m -> (c, tap, l4)
        int c   = m / 36;
        int rem = m - c * 36;
        int tap = rem >> 2;
        int l4  = rem & 3;
        short8 v;
#pragma unroll
        for (int e = 0; e < 8; ++e)
            v[e] = (short)f2bf(q[(c * 32 + l4 * 8 + e) * 9 + tap]);
        *(short8*)(wpk + ((((size_t)c * 9 + tap) * 32 + g) * 64 + l4 * 16 + l15) * 8) = v;
    }
}

// ---------------- Phase 1b: sigma_inv[b][o] = rsqrt(c^2 * sum_i wsq[o,i]*(1+s)^2 + eps) ----
__global__ __launch_bounds__(256) void sigma_kernel(const float* __restrict__ weight,
                                                    const float* __restrict__ style,
                                                    float* __restrict__ siginv) {
    __shared__ float sred[4][8];
    const int o = blockIdx.x;
    const int t = threadIdx.x;
    const float* wrow = weight + (size_t)o * KTOT;
    float acc[8] = {0.f, 0.f, 0.f, 0.f, 0.f, 0.f, 0.f, 0.f};
#pragma unroll
    for (int ii = 0; ii < 2; ++ii) {
        const int i = t * 2 + ii;
        float wsq = 0.f;
#pragma unroll
        for (int tap = 0; tap < 9; ++tap) {
            float v = wrow[i * 9 + tap];
            wsq += v * v;
        }
#pragma unroll
        for (int b = 0; b < 8; ++b) {
            float s = style[b * CIN + i] + 1.0f;
            acc[b] += wsq * s * s;
        }
    }
#pragma unroll
    for (int b = 0; b < 8; ++b) {
        float v = acc[b];
#pragma unroll
        for (int off = 32; off > 0; off >>= 1) v += __shfl_down(v, off, 64);
        if ((t & 63) == 0) sred[t >> 6][b] = v;
    }
    __syncthreads();
    if (t < 8) {
        const float S = sred[0][t] + sred[1][t] + sred[2][t] + sred[3][t];
        siginv[t * COUT + o] = rsqrtf(S * (1.0f / (float)KTOT) + 1e-8f);
    }
}

// ---------------- Phase 2: implicit-GEMM conv ----------------
// block: 512 thr = 8 waves; tile 256 o x 2 output rows x 64 cols.
// wave (og = wid&3, rp = wid>>2): 64 o x 1 row x 64 px -> acc[4][4] (64 AGPR).
// X: 4 rows x 66 slices x 32 ch per buffer, double-buffered (33.8 KB) -> 2 blocks/CU,
// 4 waves/SIMD. 16 ic-chunks of 32 ch; 9 tap-phases each; 16 MFMA/phase.
__global__ __launch_bounds__(512, 4) void conv_kernel(const unsigned short* __restrict__ wpk,
                                                      const unsigned short* __restrict__ xtp,
                                                      const float* __restrict__ siginv,
                                                      const float* __restrict__ bias,
                                                      float* __restrict__ out) {
    __shared__ __align__(16) unsigned short xs[2 * BUFSH];   // 33792 B
    // XCD-aware decode: XCD k = bid&7 owns ob = k&1 (2.36 MB weight half, L2-hot)
    const int bid = blockIdx.x;
    const int k  = bid & 7;
    const int tq = bid >> 3;            // 0..63
    const int ob = k & 1;
    const int b  = (k >> 1) * 2 + (tq >> 5);
    const int yb = tq & 31;
    const int y0 = yb * 2;

    const int tid  = threadIdx.x;
    const int lane = tid & 63;
    const int wid_u = __builtin_amdgcn_readfirstlane(tid >> 6);   // wave-uniform -> SGPR
    const int l15 = lane & 15, l4 = lane >> 4;
    const int og = wid_u & 3, rp = wid_u >> 2;
    const int g0 = ob * 16 + og * 4;    // o-frag base (frags of 16 o), scalar

    // ---- staging precompute: per-thread global srcs (advance +32 shorts per ic) ----
    // load q covers slices q*16..q*16+15; lane -> slice q*16 + (lane>>2), unit lane&3.
    const int u = lane & 3;
    const int sl0 = wid_u * 16 + (lane >> 2);          // q0 = wid_u
    const int row0 = sl0 / 66, col0 = sl0 - row0 * 66;
    const int sl1 = sl0 + 128;                          // q1 = wid_u + 8
    const int row1 = sl1 / 66, col1 = sl1 - row1 * 66;
    const int col2 = 58 + (lane >> 2);                  // q2 = 16: slices 256..263, row 3
    const unsigned short* src0 =
        xtp + ((size_t)(b * XPD + y0 + row0) * XPD + col0) * 512 + (u ^ (col0 & 3)) * 8;
    const unsigned short* src1 =
        xtp + ((size_t)(b * XPD + y0 + row1) * XPD + col1) * 512 + (u ^ (col1 & 3)) * 8;
    const unsigned short* src2 =
        xtp + ((size_t)(b * XPD + y0 + 3) * XPD + col2) * 512 + (u ^ (col2 & 3)) * 8;

    // swizzled B ds byte-voffsets (col = l15+kx, unit slot = l4 ^ (col&3))
    int vB[3];
#pragma unroll
    for (int kx = 0; kx < 3; ++kx)
        vB[kx] = (l15 + kx) * 64 + ((l4 ^ ((l15 + kx) & 3)) * 16);

    f32x4 acc[4][4];
#pragma unroll
    for (int mi = 0; mi < 4; ++mi)
#pragma unroll
        for (int j = 0; j < 4; ++j) acc[mi][j] = (f32x4){0.f, 0.f, 0.f, 0.f};

    // A base: frag addr = ((ic*9+tap)*32 + g0+mi)*512 + lane*8
    const unsigned short* wB = wpk + (size_t)g0 * 512 + lane * 8;

#define STAGE(bufp, icq)                                                                  \
    do {                                                                                  \
        unsigned short* dbase = xs + (bufp) * BUFSH + wid_u * 512;                        \
        gll16(src0 + (size_t)(icq) * 32, dbase);                                          \
        gll16(src1 + (size_t)(icq) * 32, dbase + 4096);                                   \
        if (wid_u == 0 && lane < 32)                                                      \
            gll16(src2 + (size_t)(icq) * 32, xs + (bufp) * BUFSH + 8192);                 \
    } while (0)

#define PHASE(tap, wAc, cbase)                                                            \
    do {                                                                                  \
        short8 afx[4];                                                                    \
        _Pragma("unroll") for (int mi = 0; mi < 4; ++mi)                                  \
            afx[mi] = *(const short8*)((wAc) + (tap) * 16384 + mi * 512);                 \
        short8 bfr[4];                                                                    \
        const char* bp = (const char*)xs + (cbase) +                                      \
                         (rp + (tap) / 3) * ROWB + vB[(tap) % 3];                         \
        _Pragma("unroll") for (int j = 0; j < 4; ++j)                                     \
            bfr[j] = *(const short8*)(bp + j * 1024);                                     \
        __builtin_amdgcn_s_setprio(1);                                                    \
        _Pragma("unroll") for (int mi = 0; mi < 4; ++mi)                                  \
            _Pragma("unroll") for (int j = 0; j < 4; ++j)                                 \
                acc[mi][j] = __builtin_amdgcn_mfma_f32_16x16x32_bf16(                     \
                    afx[mi], bfr[j], acc[mi][j], 0, 0, 0);                                \
        __builtin_amdgcn_s_setprio(0);                                                    \
    } while (0)

    STAGE(0, 0);
    __syncthreads();

#pragma unroll 1
    for (int ic = 0; ic < 16; ++ic) {
        if (ic < 15) STAGE((ic + 1) & 1, ic + 1);
        const unsigned short* wAc = wB + (size_t)ic * (9 * 32 * 512);
        const int cbase = (ic & 1) * (BUFSH * 2);   // bytes
#pragma unroll
        for (int tap = 0; tap < 9; ++tap) {
            PHASE(tap, wAc, cbase);
        }
        __syncthreads();
    }

    // epilogue: D-frag col = l15 (px), row = l4*4 + rr (o); scale by sigma_inv, add bias
    const int yout = y0 + rp;
#pragma unroll
    for (int mi = 0; mi < 4; ++mi) {
        const int obase = ob * 256 + og * 64 + mi * 16 + l4 * 4;
#pragma unroll
        for (int rr = 0; rr < 4; ++rr) {
            const int o = obase + rr;
            const float sv = siginv[b * COUT + o];
            const float bv = bias[o];
            float* orow = out + (((size_t)(b * COUT + o) * HH + yout) << 6);
#pragma unroll
            for (int j = 0; j < 4; ++j) {
                orow[j * 16 + l15] = acc[mi][j][rr] * sv + bv;
            }
        }
    }
#undef STAGE
#undef PHASE
}

extern "C" void kernel_launch(void* const* d_in, const int* in_sizes, int n_in,
                              void* d_out, int out_size, void* d_ws, size_t ws_size,
                              hipStream_t stream) {
    const float* x      = (const float*)d_in[0];
    const float* style  = (const float*)d_in[1];
    const float* weight = (const float*)d_in[2];
    const float* bias   = (const float*)d_in[3];
    float* out = (float*)d_out;

    unsigned short* wpk = (unsigned short*)d_ws;                  // 16*9*32*64*8 shorts (4.72 MB)
    unsigned short* xtp = wpk + (size_t)2359296;                  // 8*66*66*512 shorts (35.7 MB)
    float* siginv = (float*)(xtp + (size_t)BB * XPD * XPD * 512); // 8*512 f32

    zring_kernel<<<520, 256, 0, stream>>>(xtp);
    xpose_kernel<<<dim3(16, HH, BB), 256, 0, stream>>>(x, style, xtp);
    wpack_kernel<<<COUT, 256, 0, stream>>>(weight, wpk);
    sigma_kernel<<<COUT, 256, 0, stream>>>(weight, style, siginv);
    conv_kernel<<<512, 512, 0, stream>>>(wpk, xtp, siginv, bias, out);
}

// Round 7
// 165.946 us; speedup vs baseline: 1.0076x; 1.0076x over previous
//
#include <hip/hip_runtime.h>

#define CIN 512
#define COUT 512
#define HH 64
#define WW 64
#define BB 8
#define KTOT 4608   // 512*9

#define XPD 66                // padded spatial dim: index = coord+1, coord in -1..64
#define BUFSH (4 * 66 * 64)   // 16896 shorts per LDS buffer (4 rows x 66 slices x 64 ch)
#define ROWB (66 * 128)       // 8448 bytes per LDS input row

typedef __attribute__((ext_vector_type(8))) short short8;
typedef __attribute__((ext_vector_type(4))) float f32x4;

__device__ inline unsigned short f2bf(float f) {
    unsigned int u = __float_as_uint(f);
    u += 0x7FFFu + ((u >> 16) & 1u);   // round-to-nearest-even
    return (unsigned short)(u >> 16);
}

__device__ inline void gll16(const void* g, void* l) {
    __builtin_amdgcn_global_load_lds(
        (const __attribute__((address_space(1))) unsigned int*)g,
        (__attribute__((address_space(3))) unsigned int*)l, 16, 0, 0);
}

// ---------------- Phase -1: zero the halo ring of XTP ----------------
__global__ __launch_bounds__(256) void zring_kernel(unsigned short* __restrict__ xtp) {
    const int e = blockIdx.x * 256 + threadIdx.x;   // 520*256 >= 8*260*64
    if (e >= BB * 260 * 64) return;
    const int unit = e & 63;
    const int sa = e >> 6;           // 0..2079
    const int b = sa / 260;
    const int s = sa - b * 260;
    int yy, xx;
    if (s < 66)       { yy = 0;        xx = s; }
    else if (s < 132) { yy = 65;       xx = s - 66; }
    else if (s < 196) { yy = s - 131;  xx = 0; }     // rows 1..64
    else              { yy = s - 195;  xx = 65; }    // rows 1..64
    *(short8*)(xtp + ((size_t)(b * XPD + yy) * XPD + xx) * 512 + unit * 8) =
        (short8){0, 0, 0, 0, 0, 0, 0, 0};
}

// ------- Phase 0: x [b][i][y][x] fp32 * (1+style[b][i]) -> XTP [b][y+1][x+1][i] bf16 -------
__global__ __launch_bounds__(256) void xpose_kernel(const float* __restrict__ x,
                                                    const float* __restrict__ style,
                                                    unsigned short* __restrict__ xtp) {
    __shared__ float tile[32 * 65];
    __shared__ float sst[32];
    const int ic = blockIdx.x;   // 16 groups of 32 channels
    const int y  = blockIdx.y;
    const int b  = blockIdx.z;
    const int t  = threadIdx.x;
    if (t < 32) sst[t] = style[b * CIN + ic * 32 + t] + 1.0f;
#pragma unroll
    for (int it = 0; it < 8; ++it) {
        int e = it * 256 + t;
        int ii = e >> 6, xx = e & 63;
        tile[ii * 65 + xx] = x[(((size_t)(b * CIN + ic * 32 + ii) * HH + y) << 6) + xx];
    }
    __syncthreads();
#pragma unroll
    for (int it = 0; it < 8; ++it) {
        int g = it * 256 + t;
        int xx = g >> 5, ii = g & 31;
        xtp[((size_t)(b * XPD + y + 1) * XPD + xx + 1) * 512 + ic * 32 + ii] =
            f2bf(tile[ii * 65 + xx] * sst[ii]);
    }
}

// ---------------- Phase 1a: pack w*c into MFMA fragment layout (batch-independent) -------
// Wpk flat: (((c*9 + tap)*32 + g)*64 + lane)*8 + e ; lane = l4*16+l15 holds
//   W[o = g*16+l15][i = c*32 + l4*8 + e],  c = 16 chunks of 32 input ch.
__global__ __launch_bounds__(256) void wpack_kernel(const float* __restrict__ weight,
                                                    unsigned short* __restrict__ wpk) {
    __shared__ float q[KTOT];
    const int o = blockIdx.x;
    const int t = threadIdx.x;
    const float* wrow = weight + (size_t)o * KTOT;   // e = i*9+tap
    const float cst = 1.0f / sqrtf((float)KTOT);
#pragma unroll
    for (int it = 0; it < 18; ++it) {
        int e = it * 256 + t;
        q[e] = wrow[e] * cst;
    }
    __syncthreads();
    const int g = o >> 4, l15 = o & 15;
    for (int m = t; m < 576; m += 256) {   // m -> (c, tap, l4)
        int c   = m / 36;
        int rem = m - c * 36;
        int tap = rem >> 2;
        int l4  = rem & 3;
        short8 v;
#pragma unroll
        for (int e = 0; e < 8; ++e)
            v[e] = (short)f2bf(q[(c * 32 + l4 * 8 + e) * 9 + tap]);
        *(short8*)(wpk + ((((size_t)c * 9 + tap) * 32 + g) * 64 + l4 * 16 + l15) * 8) = v;
    }
}

// ---------------- Phase 1b: sigma_inv[b][o] = rsqrt(c^2 * sum_i wsq[o,i]*(1+s)^2 + eps) ----
__global__ __launch_bounds__(256) void sigma_kernel(const float* __restrict__ weight,
                                                    const float* __restrict__ style,
                                                    float* __restrict__ siginv) {
    __shared__ float sred[4][8];
    const int o = blockIdx.x;
    const int t = threadIdx.x;
    const float* wrow = weight + (size_t)o * KTOT;
    float acc[8] = {0.f, 0.f, 0.f, 0.f, 0.f, 0.f, 0.f, 0.f};
#pragma unroll
    for (int ii = 0; ii < 2; ++ii) {
        const int i = t * 2 + ii;
        float wsq = 0.f;
#pragma unroll
        for (int tap = 0; tap < 9; ++tap) {
            float v = wrow[i * 9 + tap];
            wsq += v * v;
        }
#pragma unroll
        for (int b = 0; b < 8; ++b) {
            float s = style[b * CIN + i] + 1.0f;
            acc[b] += wsq * s * s;
        }
    }
#pragma unroll
    for (int b = 0; b < 8; ++b) {
        float v = acc[b];
#pragma unroll
        for (int off = 32; off > 0; off >>= 1) v += __shfl_down(v, off, 64);
        if ((t & 63) == 0) sred[t >> 6][b] = v;
    }
    __syncthreads();
    if (t < 8) {
        const float S = sred[0][t] + sred[1][t] + sred[2][t] + sred[3][t];
        siginv[t * COUT + o] = rsqrtf(S * (1.0f / (float)KTOT) + 1e-8f);
    }
}

// ---------------- Phase 2: implicit-GEMM conv ----------------
// block: 512 thr = 8 waves; tile 256 o x 2 output rows x 64 cols.
// wave (og = wid&3, rp = wid>>2): 64 o x 1 row x 64 px -> acc[4][4] (64 AGPR).
// X: 4 rows x 66 slices x 64 ch per buffer (128B slices, XOR-8 swizzle = proven
// conflict-free), double-buffered (67.6 KB) -> 2 blocks/CU, 4 waves/SIMD.
// 8 ic-chunks of 64 ch; 9 taps x 2 ks phases each; 16 MFMA/phase.
__global__ __launch_bounds__(512, 4) void conv_kernel(const unsigned short* __restrict__ wpk,
                                                      const unsigned short* __restrict__ xtp,
                                                      const float* __restrict__ siginv,
                                                      const float* __restrict__ bias,
                                                      float* __restrict__ out) {
    __shared__ __align__(16) unsigned short xs[2 * BUFSH];   // 67584 B
    // XCD-aware decode: XCD k = bid&7 owns ob = k&1 (2.36 MB weight half, L2-hot)
    const int bid = blockIdx.x;
    const int k  = bid & 7;
    const int tq = bid >> 3;            // 0..63
    const int ob = k & 1;
    const int b  = (k >> 1) * 2 + (tq >> 5);
    const int yb = tq & 31;
    const int y0 = yb * 2;

    const int tid  = threadIdx.x;
    const int lane = tid & 63;
    const int wid_u = __builtin_amdgcn_readfirstlane(tid >> 6);   // wave-uniform -> SGPR
    const int l15 = lane & 15, l4 = lane >> 4;
    const int og = wid_u & 3, rp = wid_u >> 2;
    const int g0 = ob * 16 + og * 4;    // o-frag base (frags of 16 o), scalar

    // ---- staging precompute: per-thread global srcs (advance +64 shorts per ic) ----
    // wave-load q (0..32) covers slices q*8..q*8+7; lane -> slice q*8+(lane>>3),
    // phys unit = lane&7; logical unit = (lane&7) ^ (col&7) (inverse swizzle on src).
    const int up = lane & 7;
    const unsigned short* srcq[4];
#pragma unroll
    for (int t4 = 0; t4 < 4; ++t4) {
        const int sl = (wid_u + t4 * 8) * 8 + (lane >> 3);
        const int row = sl / 66, col = sl - row * 66;
        srcq[t4] = xtp + ((size_t)(b * XPD + y0 + row) * XPD + col) * 512 +
                   (up ^ (col & 7)) * 8;
    }
    const int col4 = 58 + (lane >> 3);                    // q=32: slices 256..263, row 3
    const unsigned short* src4 =
        xtp + ((size_t)(b * XPD + y0 + 3) * XPD + col4) * 512 + (up ^ (col4 & 7)) * 8;

    // swizzled B ds byte-voffsets (col = l15+kx, phys unit = (ks*4+l4) ^ (col&7))
    int vB[3][2];
#pragma unroll
    for (int kx = 0; kx < 3; ++kx)
#pragma unroll
        for (int ks = 0; ks < 2; ++ks)
            vB[kx][ks] = (l15 + kx) * 128 + (((ks * 4 + l4) ^ ((l15 + kx) & 7)) * 16);

    f32x4 acc[4][4];
#pragma unroll
    for (int mi = 0; mi < 4; ++mi)
#pragma unroll
        for (int j = 0; j < 4; ++j) acc[mi][j] = (f32x4){0.f, 0.f, 0.f, 0.f};

    // A frag addr = (((ic*2+ks)*9 + tap)*32 + g0+mi)*512 + lane*8  (shorts)
    const unsigned short* wB = wpk + (size_t)g0 * 512 + lane * 8;

#define STAGE(bufp, icq)                                                                  \
    do {                                                                                  \
        unsigned short* dbase = xs + (bufp) * BUFSH + wid_u * 512;                        \
        gll16(srcq[0] + (size_t)(icq) * 64, dbase);                                       \
        gll16(srcq[1] + (size_t)(icq) * 64, dbase + 4096);                                \
        gll16(srcq[2] + (size_t)(icq) * 64, dbase + 8192);                                \
        gll16(srcq[3] + (size_t)(icq) * 64, dbase + 12288);                               \
        if (wid_u == 0)                                                                   \
            gll16(src4 + (size_t)(icq) * 64, xs + (bufp) * BUFSH + 16384);                \
    } while (0)

#define PHASE(tap, ks, wAc, cbase)                                                        \
    do {                                                                                  \
        short8 afx[4];                                                                    \
        _Pragma("unroll") for (int mi = 0; mi < 4; ++mi)                                  \
            afx[mi] = *(const short8*)((wAc) + ((ks) * 9 + (tap)) * 16384 + mi * 512);    \
        short8 bfr[4];                                                                    \
        const char* bp = (const char*)xs + (cbase) +                                      \
                         (rp + (tap) / 3) * ROWB + vB[(tap) % 3][ks];                     \
        _Pragma("unroll") for (int j = 0; j < 4; ++j)                                     \
            bfr[j] = *(const short8*)(bp + j * 2048);                                     \
        __builtin_amdgcn_s_setprio(1);                                                    \
        _Pragma("unroll") for (int mi = 0; mi < 4; ++mi)                                  \
            _Pragma("unroll") for (int j = 0; j < 4; ++j)                                 \
                acc[mi][j] = __builtin_amdgcn_mfma_f32_16x16x32_bf16(                     \
                    afx[mi], bfr[j], acc[mi][j], 0, 0, 0);                                \
        __builtin_amdgcn_s_setprio(0);                                                    \
    } while (0)

    STAGE(0, 0);
    __syncthreads();

#pragma unroll 1
    for (int ic = 0; ic < 8; ++ic) {
        if (ic < 7) STAGE((ic + 1) & 1, ic + 1);
        const unsigned short* wAc = wB + (size_t)ic * (2 * 9 * 32 * 512);
        const int cbase = (ic & 1) * (BUFSH * 2);   // bytes
#pragma unroll
        for (int tap = 0; tap < 9; ++tap) {
            PHASE(tap, 0, wAc, cbase);
            PHASE(tap, 1, wAc, cbase);
        }
        __syncthreads();
    }

    // epilogue: D-frag col = l15 (px), row = l4*4 + rr (o); scale by sigma_inv, add bias
    const int yout = y0 + rp;
#pragma unroll
    for (int mi = 0; mi < 4; ++mi) {
        const int obase = ob * 256 + og * 64 + mi * 16 + l4 * 4;
#pragma unroll
        for (int rr = 0; rr < 4; ++rr) {
            const int o = obase + rr;
            const float sv = siginv[b * COUT + o];
            const float bv = bias[o];
            float* orow = out + (((size_t)(b * COUT + o) * HH + yout) << 6);
#pragma unroll
            for (int j = 0; j < 4; ++j) {
                orow[j * 16 + l15] = acc[mi][j][rr] * sv + bv;
            }
        }
    }
#undef STAGE
#undef PHASE
}

extern "C" void kernel_launch(void* const* d_in, const int* in_sizes, int n_in,
                              void* d_out, int out_size, void* d_ws, size_t ws_size,
                              hipStream_t stream) {
    const float* x      = (const float*)d_in[0];
    const float* style  = (const float*)d_in[1];
    const float* weight = (const float*)d_in[2];
    const float* bias   = (const float*)d_in[3];
    float* out = (float*)d_out;

    unsigned short* wpk = (unsigned short*)d_ws;                  // 16*9*32*64*8 shorts (4.72 MB)
    unsigned short* xtp = wpk + (size_t)2359296;                  // 8*66*66*512 shorts (35.7 MB)
    float* siginv = (float*)(xtp + (size_t)BB * XPD * XPD * 512); // 8*512 f32

    zring_kernel<<<520, 256, 0, stream>>>(xtp);
    xpose_kernel<<<dim3(16, HH, BB), 256, 0, stream>>>(x, style, xtp);
    wpack_kernel<<<COUT, 256, 0, stream>>>(weight, wpk);
    sigma_kernel<<<COUT, 256, 0, stream>>>(weight, style, siginv);
    conv_kernel<<<512, 512, 0, stream>>>(wpk, xtp, siginv, bias, out);
}